// Round 3
// baseline (247.742 us; speedup 1.0000x reference)
//
#include <hip/hip_runtime.h>
#include <hip/hip_bf16.h>

// DFAChebNet forward.
//  layer: x@W0 + (agg(x)-x)@W1 + b == x@(W0-W1) + agg(x@W1) + b   (project first)
//  aggregation: CSR pull-gather; CSR built by LDS-staged counting sort.
//  R14: revert persistence (R13 regression: block churn IS the cross-node
//  overlap). Gather kernels leaned out: independent loads (xa / ha,dinv)
//  hoisted above the gather loop; proj2 matvec d-split (lane computes 4-k
//  partials for 4 outputs, xor-reduce over d bits) -- 8 shuffles instead of
//  20, role-split epilogue by d, <=1 f2e4m3 per lane, coalesced byte stores.

#include <hip/hip_fp16.h>

constexpr int NN   = 100000;
constexpr int NE   = 1600000;
constexpr int FIN  = 128;
constexpr int HID  = 16;
constexpr int NCLS = 32;

constexpr int RB    = 256;                         // rows per bucket
constexpr int NBKT  = (NN + RB - 1) / RB;          // 391
constexpr int EPB   = 4096;                        // edges per partition block
constexpr int EPT   = EPB / 256;                   // 16 edges per thread
constexpr int GP    = (NE + EPB - 1) / EPB;        // 391
constexpr int CAP   = 8192;                        // bucket slot capacity (mean 4096)
constexpr int NTILE = NN / 16;                     // 6250 MFMA tiles (exact)

typedef float f32x2 __attribute__((ext_vector_type(2)));
typedef float f32x4 __attribute__((ext_vector_type(4)));
typedef short bf16x8 __attribute__((ext_vector_type(8)));

#if defined(__has_builtin)
#if __has_builtin(__builtin_amdgcn_cvt_pk_f32_fp8)
#define HAVE_CVT_FP8 1
#endif
#endif

// fp8 e4m3fn encode (RNE, subnormals flushed to 0, clamp at 448)
static __device__ __forceinline__ unsigned int f2e4m3(float f) {
    union { float f; unsigned int u; } v; v.f = f;
    unsigned int s = (v.u >> 24) & 0x80u;
    unsigned int au = v.u & 0x7fffffffu;
    if (au > 0x43E00000u) au = 0x43E00000u;        // clamp to 448
    au += 0x7ffffu + ((au >> 20) & 1u);            // RNE into 3-bit mantissa
    int e4 = (int)(au >> 23) - 120;                // 127-7
    unsigned int m = (au >> 20) & 7u;
    unsigned int byte = (e4 <= 0) ? 0u : (((unsigned int)e4 << 3) | m);
    return s | byte;
}
// 4 packed fp8 -> acc[0..3] += w * val
static __device__ __forceinline__ void fp8x4_fma(unsigned int v, float w, float* acc) {
#ifdef HAVE_CVT_FP8
    f32x2 lo = __builtin_amdgcn_cvt_pk_f32_fp8((int)v, false);
    f32x2 hi = __builtin_amdgcn_cvt_pk_f32_fp8((int)v, true);
    acc[0] += w * lo.x; acc[1] += w * lo.y;
    acc[2] += w * hi.x; acc[3] += w * hi.y;
#else
#pragma unroll
    for (int i = 0; i < 4; i++) {
        unsigned int b = (v >> (8 * i)) & 0xffu;
        float f = __int_as_float((int)(((b & 0x80u) << 24) | ((b & 0x7fu) << 20))) * 0x1p120f;
        acc[i] += w * f;
    }
#endif
}
// bf16 RNE
static __device__ __forceinline__ unsigned short f2bf(float f) {
    union { float f; unsigned int u; } v; v.f = f;
    unsigned int r = v.u + 0x7fffu + ((v.u >> 16) & 1u);
    return (unsigned short)(r >> 16);
}
// edge record: col(17 bits) | w(15 bits = signless bf16, RNE)
static __device__ __forceinline__ unsigned int wpack(float wf) {
    unsigned int b = __float_as_uint(wf) + 0x8000u;
    return (b >> 16) & 0x7fffu;
}
static __device__ __forceinline__ float wdec(unsigned int u) {
    return __uint_as_float((u >> 17) << 16);
}

// ---- zero the bucket cursors ----
__global__ void k_zero_cur(int* __restrict__ bucketCursor) {
    int i = blockIdx.x * blockDim.x + threadIdx.x;
    if (i < NBKT) bucketCursor[i] = 0;
}

// ---- pass B: LDS-staged partition; atomic reservation into slotted buffer ----
__global__ __launch_bounds__(256) void k_partition(
    const int* __restrict__ row, const int* __restrict__ col,
    const float* __restrict__ w, int* __restrict__ bucketCursor,
    int2* __restrict__ partS) {
    __shared__ int2 stage[EPB];              // 32KB
    __shared__ unsigned short sbkt[EPB];     // 8KB
    __shared__ int cnt[NBKT];
    __shared__ int lofs[NBKT];
    __shared__ int cursor[NBKT];
    __shared__ int gbase[NBKT];
    __shared__ int sa[512], sb[512];
    int tid = threadIdx.x;
    long ebase = (long)blockIdx.x * EPB;
    int rr[EPT]; int cc[EPT]; float wv[EPT];
#pragma unroll
    for (int i = 0; i < EPT; i++) {
        long e = ebase + i * 256 + tid;
        if (e < NE) { rr[i] = row[e]; cc[i] = col[e]; wv[i] = w[e]; }
        else rr[i] = -1;
    }
    for (int i = tid; i < NBKT; i += 256) cnt[i] = 0;
    __syncthreads();
#pragma unroll
    for (int i = 0; i < EPT; i++)
        if (rr[i] >= 0) atomicAdd(&cnt[rr[i] >> 8], 1);
    __syncthreads();
    for (int i = tid; i < 512; i += 256) sa[i] = (i < NBKT) ? cnt[i] : 0;
    __syncthreads();
    int* src = sa; int* dst = sb;
    for (int off = 1; off < 512; off <<= 1) {
        for (int i = tid; i < 512; i += 256)
            dst[i] = src[i] + ((i >= off) ? src[i - off] : 0);
        __syncthreads();
        int* t = src; src = dst; dst = t;
    }
    for (int i = tid; i < NBKT; i += 256) {
        int ex = src[i] - cnt[i];
        lofs[i] = ex;
        cursor[i] = ex;
        int go = (cnt[i] > 0) ? atomicAdd(&bucketCursor[i], cnt[i]) : 0;
        gbase[i] = i * CAP + go;
    }
    __syncthreads();
#pragma unroll
    for (int i = 0; i < EPT; i++) {
        if (rr[i] >= 0) {
            int b = rr[i] >> 8;
            int p = atomicAdd(&cursor[b], 1);
            int2 v;
            v.x = cc[i] | ((rr[i] & 255) << 17);
            v.y = __float_as_int(wv[i]);
            stage[p] = v;
            sbkt[p] = (unsigned short)b;
        }
    }
    __syncthreads();
    int total = (int)min((long)EPB, NE - ebase);
    for (int i = tid; i < total; i += 256) {
        int b = sbkt[i];
        partS[gbase[b] + (i - lofs[b])] = stage[i];
    }
}

// ---- pass C: per-bucket sort by row; direct scatter to packed 4B CSR.
// No 64KB LDS stage: partC bucket region is block-private, L2 absorbs the 4B
// scattered writes. dinv via LDS float atomics. Bucket prefix-scan inlined.
__global__ __launch_bounds__(256) void k_bucket_sort(
    const int2* __restrict__ partS, const int* __restrict__ bucketCursor,
    unsigned int* __restrict__ partC, int* __restrict__ rowptr,
    float* __restrict__ dinv) {
    __shared__ int hist[RB];
    __shared__ int cursor[RB];
    __shared__ float dsum[RB];
    __shared__ int wtot[4];
    __shared__ int red[4];
    int b = blockIdx.x;
    int tid = threadIdx.x;
    int lane = tid & 63, wv = tid >> 6;
    // inline exclusive scan: start = sum_{i<b} count_i
    int partial = 0;
    for (int i = tid; i < b; i += 256) partial += bucketCursor[i];
#pragma unroll
    for (int off = 1; off < 64; off <<= 1) partial += __shfl_xor(partial, off, 64);
    if (lane == 0) red[wv] = partial;
    hist[tid] = 0;
    dsum[tid] = 0.f;
    __syncthreads();
    int start = red[0] + red[1] + red[2] + red[3];
    int count = bucketCursor[b];
    const int2* src = partS + (long)b * CAP;
    for (int i = tid; i < count; i += 256)
        atomicAdd(&hist[((unsigned)src[i].x >> 17) & 255], 1);
    __syncthreads();
    int v = hist[tid];
    int sc = v;
#pragma unroll
    for (int off = 1; off < 64; off <<= 1) {
        int up = __shfl_up(sc, off, 64);
        if (lane >= off) sc += up;
    }
    if (lane == 63) wtot[wv] = sc;
    __syncthreads();
    int add = 0;
    for (int w2 = 0; w2 < wv; w2++) add += wtot[w2];
    int ex = sc + add - v;
    int node = b * RB + tid;
    if (node <= NN) rowptr[node] = start + ex;   // node==NN -> NE (last bucket)
    cursor[tid] = ex;
    __syncthreads();
    for (int i = tid; i < count; i += 256) {
        int2 p = src[i];
        int rl = ((unsigned)p.x >> 17) & 255;
        int pos = atomicAdd(&cursor[rl], 1);
        float wf = __int_as_float(p.y);
        partC[start + pos] = ((unsigned)p.x & 0x1FFFFu) | (wpack(wf) << 17);
        atomicAdd(&dsum[rl], wf);
    }
    __syncthreads();
    if (node < NN) {
        float dsv = dsum[tid];
        dinv[node] = dsv > 0.f ? rsqrtf(dsv) : 0.f;
    }
}

// xa = x@(W1_0-W1_1)+b1 (fp32) ; xb' = dinv[n] * (x@W1_1) (fp8 e4m3).
// MFMA 16x16x32 bf16: 1 wave = 16 nodes. W frags in VGPRs (built once);
// A = 8 float4 loads/lane; acc0 = x@W1_0, acc1 = x@W1_1.
__global__ __launch_bounds__(256) void k_proj1(
    const float* __restrict__ x, const float* __restrict__ W0,
    const float* __restrict__ W1, const float* __restrict__ b1,
    const float* __restrict__ dinv,
    float* __restrict__ xa, unsigned char* __restrict__ xb8) {
    int wid = (int)(((long)blockIdx.x * 256 + threadIdx.x) >> 6);   // tile id
    if (wid >= NTILE) return;
    int lane = threadIdx.x & 63;
    int col = lane & 15, quad = lane >> 4;

    // B fragments: B[k = kb*32 + quad*8 + j][n = col], once per wave.
    bf16x8 bfrag[2][4];
#pragma unroll
    for (int mat = 0; mat < 2; mat++) {
        const float* W = mat ? W1 : W0;
#pragma unroll
        for (int kb = 0; kb < 4; kb++) {
            bf16x8 f;
#pragma unroll
            for (int j = 0; j < 8; j++)
                f[j] = (short)f2bf(W[(kb * 32 + quad * 8 + j) * HID + col]);
            bfrag[mat][kb] = f;
        }
    }

    // A: lane's share of the tile = x[node = wid*16+col][quad*8 .. ] per kblock
    const float* xrow = x + ((long)wid * 16 + col) * FIN + quad * 8;
    float4 xb[8];
#pragma unroll
    for (int kb = 0; kb < 4; kb++) {
        xb[2 * kb]     = *(const float4*)(xrow + kb * 32);
        xb[2 * kb + 1] = *(const float4*)(xrow + kb * 32 + 4);
    }
    f32x4 acc0 = {0.f, 0.f, 0.f, 0.f}, acc1 = {0.f, 0.f, 0.f, 0.f};
#pragma unroll
    for (int kb = 0; kb < 4; kb++) {
        float4 a0 = xb[2 * kb], a1 = xb[2 * kb + 1];
        bf16x8 af;
        af[0] = (short)f2bf(a0.x); af[1] = (short)f2bf(a0.y);
        af[2] = (short)f2bf(a0.z); af[3] = (short)f2bf(a0.w);
        af[4] = (short)f2bf(a1.x); af[5] = (short)f2bf(a1.y);
        af[6] = (short)f2bf(a1.z); af[7] = (short)f2bf(a1.w);
        acc0 = __builtin_amdgcn_mfma_f32_16x16x32_bf16(af, bfrag[0][kb], acc0, 0, 0, 0);
        acc1 = __builtin_amdgcn_mfma_f32_16x16x32_bf16(af, bfrag[1][kb], acc1, 0, 0, 0);
    }

    // C layout: col = lane&15, row = quad*4 + r
    float b1v = b1[col];
#pragma unroll
    for (int r = 0; r < 4; r++) {
        long node = (long)wid * 16 + quad * 4 + r;
        float a0 = acc0[r], a1 = acc1[r];
        xa[node * HID + col] = a0 - a1 + b1v;
        float dn = dinv[node];
        xb8[node * HID + col] = (unsigned char)f2e4m3(dn * a1);
    }
}

// Fused layer-1 gather + layer-2 projection (R14).
//  1 wave = 1 node (block churn provides cross-node overlap).
//  agg[k] = dinv[n] * sum_j w_j * xb'[c_j,k]  (p=edge parity 0..15, d=dword)
//  After p-reduce every lane holds its d-quad h[4d..4d+3]. Matvec d-split:
//  lane (d,p) accumulates its 4 k's into 4 outputs {W0/W1 x cls p/p+16},
//  xor-reduce over d bits (8 shuffles total). Epilogue role-split by d:
//  d0: ha cls p, d1: ha cls p+16, d2: hb8 cls p, d3: hb8 cls p+16.
__global__ __launch_bounds__(256) void k_gather1_proj2(
    const int* __restrict__ rowptr, const unsigned int* __restrict__ partC,
    const float* __restrict__ dinv, const unsigned char* __restrict__ xb8,
    const float* __restrict__ xa, const float* __restrict__ W0,
    const float* __restrict__ W1, const float* __restrict__ b2,
    float* __restrict__ ha, unsigned char* __restrict__ hb8) {
    long t = (long)blockIdx.x * 256 + threadIdx.x;
    int n = (int)(t >> 6);
    if (n >= NN) return;
    int lane = threadIdx.x & 63;
    int d = lane & 3, p = lane >> 2;

    int s = rowptr[n], e = rowptr[n + 1];
    float dn = dinv[n];
    float4 xav = *(const float4*)(xa + (long)n * HID + d * 4);   // hoisted

    // weight fragment: wf[t][i], k = 4d+i; t: 0=W0[.,p] 1=W0[.,p+16]
    //                                        2=W1[.,p] 3=W1[.,p+16]
    float wf[4][4];
#pragma unroll
    for (int i = 0; i < 4; i++) {
        int k = 4 * d + i;
        wf[0][i] = W0[k * NCLS + p];
        wf[1][i] = W0[k * NCLS + p + 16];
        wf[2][i] = W1[k * NCLS + p];
        wf[3][i] = W1[k * NCLS + p + 16];
    }

    float acc[4] = {0.f, 0.f, 0.f, 0.f};
    for (int j = s + p; j < e; j += 16) {
        unsigned int u = partC[j];
        unsigned int v = *(const unsigned int*)(xb8 + (u & 0x1FFFF) * HID + d * 4);
        fp8x4_fma(v, wdec(u), acc);
    }
#pragma unroll
    for (int i = 0; i < 4; i++) {
        acc[i] += __shfl_xor(acc[i], 4);
        acc[i] += __shfl_xor(acc[i], 8);
        acc[i] += __shfl_xor(acc[i], 16);
        acc[i] += __shfl_xor(acc[i], 32);
    }
    // h quadrant for this lane's d
    float hq[4];
    hq[0] = fmaxf(xav.x + dn * acc[0], 0.f);
    hq[1] = fmaxf(xav.y + dn * acc[1], 0.f);
    hq[2] = fmaxf(xav.z + dn * acc[2], 0.f);
    hq[3] = fmaxf(xav.w + dn * acc[3], 0.f);
    // 4-k partials for 4 outputs, then reduce across d (lane bits 0-1)
    float pt[4] = {0.f, 0.f, 0.f, 0.f};
#pragma unroll
    for (int i = 0; i < 4; i++) {
        pt[0] += hq[i] * wf[0][i];
        pt[1] += hq[i] * wf[1][i];
        pt[2] += hq[i] * wf[2][i];
        pt[3] += hq[i] * wf[3][i];
    }
#pragma unroll
    for (int tt = 0; tt < 4; tt++) {
        pt[tt] += __shfl_xor(pt[tt], 1);
        pt[tt] += __shfl_xor(pt[tt], 2);
    }
    // role-split epilogue
    if (d == 0) {
        ha[(long)n * NCLS + p] = pt[0] - pt[2] + b2[p];
    } else if (d == 1) {
        ha[(long)n * NCLS + p + 16] = pt[1] - pt[3] + b2[p + 16];
    } else if (d == 2) {
        hb8[(long)n * NCLS + p] = (unsigned char)f2e4m3(dn * pt[2]);
    } else {
        hb8[(long)n * NCLS + p + 16] = (unsigned char)f2e4m3(dn * pt[3]);
    }
}

// out[n,:] = log_softmax(ha[n,:] + dinv[n]*sum_j w_j*hb'[c_j,:]).
// 1 wave = 1 node; lane = (parity p 0..7, dword d 0..7); unroll 2.
// R14: ha/dinv loads hoisted above the gather loop.
__global__ __launch_bounds__(256) void k_gather2_lsm(
    const int* __restrict__ rowptr, const unsigned int* __restrict__ partC,
    const float* __restrict__ dinv, const float* __restrict__ ha,
    const unsigned char* __restrict__ hb8, float* __restrict__ out) {
    long t = (long)blockIdx.x * 256 + threadIdx.x;
    int n = (int)(t >> 6);
    if (n >= NN) return;
    int lane = threadIdx.x & 63;
    int d = lane & 7, p = lane >> 3;
    int s = rowptr[n], e = rowptr[n + 1];
    float dn = dinv[n];
    float4 hv = *(const float4*)(ha + (long)n * NCLS + d * 4);   // hoisted
    float acc[4] = {0.f, 0.f, 0.f, 0.f};
    int j = s + p;
    for (; j + 8 < e; j += 16) {
        unsigned int u0 = partC[j], u1 = partC[j + 8];
        unsigned int v0 = *(const unsigned int*)(hb8 + (u0 & 0x1FFFF) * NCLS + d * 4);
        unsigned int v1 = *(const unsigned int*)(hb8 + (u1 & 0x1FFFF) * NCLS + d * 4);
        fp8x4_fma(v0, wdec(u0), acc);
        fp8x4_fma(v1, wdec(u1), acc);
    }
    if (j < e) {
        unsigned int u0 = partC[j];
        unsigned int v0 = *(const unsigned int*)(hb8 + (u0 & 0x1FFFF) * NCLS + d * 4);
        fp8x4_fma(v0, wdec(u0), acc);
    }
#pragma unroll
    for (int i = 0; i < 4; i++) {
        acc[i] += __shfl_xor(acc[i], 8);
        acc[i] += __shfl_xor(acc[i], 16);
        acc[i] += __shfl_xor(acc[i], 32);
    }
    float v0 = dn * acc[0] + hv.x;
    float v1 = dn * acc[1] + hv.y;
    float v2 = dn * acc[2] + hv.z;
    float v3 = dn * acc[3] + hv.w;
    float m = fmaxf(fmaxf(v0, v1), fmaxf(v2, v3));
    m = fmaxf(m, __shfl_xor(m, 1));
    m = fmaxf(m, __shfl_xor(m, 2));
    m = fmaxf(m, __shfl_xor(m, 4));
    float sum = __expf(v0 - m) + __expf(v1 - m) + __expf(v2 - m) + __expf(v3 - m);
    sum += __shfl_xor(sum, 1);
    sum += __shfl_xor(sum, 2);
    sum += __shfl_xor(sum, 4);
    float ls = logf(sum);
    if (p == 0) {
        float4 o; o.x = v0 - m - ls; o.y = v1 - m - ls;
        o.z = v2 - m - ls; o.w = v3 - m - ls;
        *(float4*)(out + (long)n * NCLS + d * 4) = o;
    }
}

extern "C" void kernel_launch(void* const* d_in, const int* in_sizes, int n_in,
                              void* d_out, int out_size, void* d_ws, size_t ws_size,
                              hipStream_t stream) {
    const float* x    = (const float*)d_in[0];
    const int*   ei   = (const int*)d_in[1];
    const float* ew   = (const float*)d_in[2];
    const float* W1_0 = (const float*)d_in[3];
    const float* W1_1 = (const float*)d_in[4];
    const float* b1   = (const float*)d_in[5];
    const float* W2_0 = (const float*)d_in[6];
    const float* W2_1 = (const float*)d_in[7];
    const float* b2   = (const float*)d_in[8];
    float* out = (float*)d_out;

    const int* row = ei;
    const int* col = ei + NE;

    char* ws = (char*)d_ws;
    int2*  partS     = (int2*)ws;                 ws += sizeof(int2) * (long)NBKT * CAP;
    unsigned int* partC = (unsigned int*)ws;      ws += sizeof(int) * NE;
    int*   bucketCursor = (int*)ws;               ws += sizeof(int) * NBKT;
    int*   rowptr    = (int*)ws;                  ws += sizeof(int) * (NN + 4);
    float* dinv      = (float*)ws;                ws += sizeof(float) * NN;
    float* xa        = (float*)ws;                ws += sizeof(float) * NN * HID;
    float* ha        = (float*)ws;                ws += sizeof(float) * NN * NCLS;
    unsigned char* xb8 = (unsigned char*)ws;      ws += sizeof(char) * NN * HID;
    unsigned char* hb8 = (unsigned char*)ws;      ws += sizeof(char) * NN * NCLS;

    k_zero_cur<<<(NBKT + 255) / 256, 256, 0, stream>>>(bucketCursor);
    k_partition<<<GP, 256, 0, stream>>>(row, col, ew, bucketCursor, partS);
    k_bucket_sort<<<NBKT, 256, 0, stream>>>(partS, bucketCursor, partC, rowptr, dinv);
    k_proj1<<<(NTILE * 64 + 255) / 256, 256, 0, stream>>>(x, W1_0, W1_1, b1, dinv, xa, xb8);
    {
        long th = (long)NN * 64;
        k_gather1_proj2<<<(int)((th + 255) / 256), 256, 0, stream>>>(
            rowptr, partC, dinv, xb8, xa, W2_0, W2_1, b2, ha, hb8);
    }
    {
        long th = (long)NN * 64;
        k_gather2_lsm<<<(int)((th + 255) / 256), 256, 0, stream>>>(rowptr, partC, dinv, ha, hb8, out);
    }
}

// Round 4
// 234.563 us; speedup vs baseline: 1.0562x; 1.0562x over previous
//
#include <hip/hip_runtime.h>
#include <hip/hip_bf16.h>

// DFAChebNet forward.
//  layer: x@W0 + (agg(x)-x)@W1 + b == x@(W0-W1) + agg(x@W1) + b   (project first)
//  aggregation: CSR pull-gather; CSR built by LDS-staged counting sort.
//  R15: gather kernels = R12 math (measured best) + DUAL-NODE WAVES. Each
//  wave owns the adjacent pair (2w, 2w+1); the two gather chains are
//  explicitly interleaved (both partC loads in flight, both xb8 loads in
//  flight, both shuffle-reduces interleaved) => 2 independent latency chains
//  per wave. Adjacent pairs share partC cache lines. Epilogues run
//  sequentially, R12-verbatim. R13 (serial multinode) and R14 (d-split
//  epilogue) both regressed; this is the ILP-without-serialization variant.

#include <hip/hip_fp16.h>

constexpr int NN   = 100000;
constexpr int NE   = 1600000;
constexpr int FIN  = 128;
constexpr int HID  = 16;
constexpr int NCLS = 32;

constexpr int RB    = 256;                         // rows per bucket
constexpr int NBKT  = (NN + RB - 1) / RB;          // 391
constexpr int EPB   = 4096;                        // edges per partition block
constexpr int EPT   = EPB / 256;                   // 16 edges per thread
constexpr int GP    = (NE + EPB - 1) / EPB;        // 391
constexpr int CAP   = 8192;                        // bucket slot capacity (mean 4096)
constexpr int NTILE = NN / 16;                     // 6250 MFMA tiles (exact)
constexpr int NPAIR = NN / 2;                      // 50000 dual-node waves

typedef float f32x2 __attribute__((ext_vector_type(2)));
typedef float f32x4 __attribute__((ext_vector_type(4)));
typedef short bf16x8 __attribute__((ext_vector_type(8)));

#if defined(__has_builtin)
#if __has_builtin(__builtin_amdgcn_cvt_pk_f32_fp8)
#define HAVE_CVT_FP8 1
#endif
#endif

// fp8 e4m3fn encode (RNE, subnormals flushed to 0, clamp at 448)
static __device__ __forceinline__ unsigned int f2e4m3(float f) {
    union { float f; unsigned int u; } v; v.f = f;
    unsigned int s = (v.u >> 24) & 0x80u;
    unsigned int au = v.u & 0x7fffffffu;
    if (au > 0x43E00000u) au = 0x43E00000u;        // clamp to 448
    au += 0x7ffffu + ((au >> 20) & 1u);            // RNE into 3-bit mantissa
    int e4 = (int)(au >> 23) - 120;                // 127-7
    unsigned int m = (au >> 20) & 7u;
    unsigned int byte = (e4 <= 0) ? 0u : (((unsigned int)e4 << 3) | m);
    return s | byte;
}
// 4 packed fp8 -> acc[0..3] += w * val
static __device__ __forceinline__ void fp8x4_fma(unsigned int v, float w, float* acc) {
#ifdef HAVE_CVT_FP8
    f32x2 lo = __builtin_amdgcn_cvt_pk_f32_fp8((int)v, false);
    f32x2 hi = __builtin_amdgcn_cvt_pk_f32_fp8((int)v, true);
    acc[0] += w * lo.x; acc[1] += w * lo.y;
    acc[2] += w * hi.x; acc[3] += w * hi.y;
#else
#pragma unroll
    for (int i = 0; i < 4; i++) {
        unsigned int b = (v >> (8 * i)) & 0xffu;
        float f = __int_as_float((int)(((b & 0x80u) << 24) | ((b & 0x7fu) << 20))) * 0x1p120f;
        acc[i] += w * f;
    }
#endif
}
// bf16 RNE
static __device__ __forceinline__ unsigned short f2bf(float f) {
    union { float f; unsigned int u; } v; v.f = f;
    unsigned int r = v.u + 0x7fffu + ((v.u >> 16) & 1u);
    return (unsigned short)(r >> 16);
}
// edge record: col(17 bits) | w(15 bits = signless bf16, RNE)
static __device__ __forceinline__ unsigned int wpack(float wf) {
    unsigned int b = __float_as_uint(wf) + 0x8000u;
    return (b >> 16) & 0x7fffu;
}
static __device__ __forceinline__ float wdec(unsigned int u) {
    return __uint_as_float((u >> 17) << 16);
}

// ---- zero the bucket cursors ----
__global__ void k_zero_cur(int* __restrict__ bucketCursor) {
    int i = blockIdx.x * blockDim.x + threadIdx.x;
    if (i < NBKT) bucketCursor[i] = 0;
}

// ---- pass B: LDS-staged partition; atomic reservation into slotted buffer ----
__global__ __launch_bounds__(256) void k_partition(
    const int* __restrict__ row, const int* __restrict__ col,
    const float* __restrict__ w, int* __restrict__ bucketCursor,
    int2* __restrict__ partS) {
    __shared__ int2 stage[EPB];              // 32KB
    __shared__ unsigned short sbkt[EPB];     // 8KB
    __shared__ int cnt[NBKT];
    __shared__ int lofs[NBKT];
    __shared__ int cursor[NBKT];
    __shared__ int gbase[NBKT];
    __shared__ int sa[512], sb[512];
    int tid = threadIdx.x;
    long ebase = (long)blockIdx.x * EPB;
    int rr[EPT]; int cc[EPT]; float wv[EPT];
#pragma unroll
    for (int i = 0; i < EPT; i++) {
        long e = ebase + i * 256 + tid;
        if (e < NE) { rr[i] = row[e]; cc[i] = col[e]; wv[i] = w[e]; }
        else rr[i] = -1;
    }
    for (int i = tid; i < NBKT; i += 256) cnt[i] = 0;
    __syncthreads();
#pragma unroll
    for (int i = 0; i < EPT; i++)
        if (rr[i] >= 0) atomicAdd(&cnt[rr[i] >> 8], 1);
    __syncthreads();
    for (int i = tid; i < 512; i += 256) sa[i] = (i < NBKT) ? cnt[i] : 0;
    __syncthreads();
    int* src = sa; int* dst = sb;
    for (int off = 1; off < 512; off <<= 1) {
        for (int i = tid; i < 512; i += 256)
            dst[i] = src[i] + ((i >= off) ? src[i - off] : 0);
        __syncthreads();
        int* t = src; src = dst; dst = t;
    }
    for (int i = tid; i < NBKT; i += 256) {
        int ex = src[i] - cnt[i];
        lofs[i] = ex;
        cursor[i] = ex;
        int go = (cnt[i] > 0) ? atomicAdd(&bucketCursor[i], cnt[i]) : 0;
        gbase[i] = i * CAP + go;
    }
    __syncthreads();
#pragma unroll
    for (int i = 0; i < EPT; i++) {
        if (rr[i] >= 0) {
            int b = rr[i] >> 8;
            int p = atomicAdd(&cursor[b], 1);
            int2 v;
            v.x = cc[i] | ((rr[i] & 255) << 17);
            v.y = __float_as_int(wv[i]);
            stage[p] = v;
            sbkt[p] = (unsigned short)b;
        }
    }
    __syncthreads();
    int total = (int)min((long)EPB, NE - ebase);
    for (int i = tid; i < total; i += 256) {
        int b = sbkt[i];
        partS[gbase[b] + (i - lofs[b])] = stage[i];
    }
}

// ---- pass C: per-bucket sort by row; direct scatter to packed 4B CSR.
// No 64KB LDS stage: partC bucket region is block-private, L2 absorbs the 4B
// scattered writes. dinv via LDS float atomics. Bucket prefix-scan inlined.
__global__ __launch_bounds__(256) void k_bucket_sort(
    const int2* __restrict__ partS, const int* __restrict__ bucketCursor,
    unsigned int* __restrict__ partC, int* __restrict__ rowptr,
    float* __restrict__ dinv) {
    __shared__ int hist[RB];
    __shared__ int cursor[RB];
    __shared__ float dsum[RB];
    __shared__ int wtot[4];
    __shared__ int red[4];
    int b = blockIdx.x;
    int tid = threadIdx.x;
    int lane = tid & 63, wv = tid >> 6;
    // inline exclusive scan: start = sum_{i<b} count_i
    int partial = 0;
    for (int i = tid; i < b; i += 256) partial += bucketCursor[i];
#pragma unroll
    for (int off = 1; off < 64; off <<= 1) partial += __shfl_xor(partial, off, 64);
    if (lane == 0) red[wv] = partial;
    hist[tid] = 0;
    dsum[tid] = 0.f;
    __syncthreads();
    int start = red[0] + red[1] + red[2] + red[3];
    int count = bucketCursor[b];
    const int2* src = partS + (long)b * CAP;
    for (int i = tid; i < count; i += 256)
        atomicAdd(&hist[((unsigned)src[i].x >> 17) & 255], 1);
    __syncthreads();
    int v = hist[tid];
    int sc = v;
#pragma unroll
    for (int off = 1; off < 64; off <<= 1) {
        int up = __shfl_up(sc, off, 64);
        if (lane >= off) sc += up;
    }
    if (lane == 63) wtot[wv] = sc;
    __syncthreads();
    int add = 0;
    for (int w2 = 0; w2 < wv; w2++) add += wtot[w2];
    int ex = sc + add - v;
    int node = b * RB + tid;
    if (node <= NN) rowptr[node] = start + ex;   // node==NN -> NE (last bucket)
    cursor[tid] = ex;
    __syncthreads();
    for (int i = tid; i < count; i += 256) {
        int2 p = src[i];
        int rl = ((unsigned)p.x >> 17) & 255;
        int pos = atomicAdd(&cursor[rl], 1);
        float wf = __int_as_float(p.y);
        partC[start + pos] = ((unsigned)p.x & 0x1FFFFu) | (wpack(wf) << 17);
        atomicAdd(&dsum[rl], wf);
    }
    __syncthreads();
    if (node < NN) {
        float dsv = dsum[tid];
        dinv[node] = dsv > 0.f ? rsqrtf(dsv) : 0.f;
    }
}

// xa = x@(W1_0-W1_1)+b1 (fp32) ; xb' = dinv[n] * (x@W1_1) (fp8 e4m3).
// MFMA 16x16x32 bf16: 1 wave = 16 nodes. W frags in VGPRs (built once);
// A = 8 float4 loads/lane; acc0 = x@W1_0, acc1 = x@W1_1.
__global__ __launch_bounds__(256) void k_proj1(
    const float* __restrict__ x, const float* __restrict__ W0,
    const float* __restrict__ W1, const float* __restrict__ b1,
    const float* __restrict__ dinv,
    float* __restrict__ xa, unsigned char* __restrict__ xb8) {
    int wid = (int)(((long)blockIdx.x * 256 + threadIdx.x) >> 6);   // tile id
    if (wid >= NTILE) return;
    int lane = threadIdx.x & 63;
    int col = lane & 15, quad = lane >> 4;

    // B fragments: B[k = kb*32 + quad*8 + j][n = col], once per wave.
    bf16x8 bfrag[2][4];
#pragma unroll
    for (int mat = 0; mat < 2; mat++) {
        const float* W = mat ? W1 : W0;
#pragma unroll
        for (int kb = 0; kb < 4; kb++) {
            bf16x8 f;
#pragma unroll
            for (int j = 0; j < 8; j++)
                f[j] = (short)f2bf(W[(kb * 32 + quad * 8 + j) * HID + col]);
            bfrag[mat][kb] = f;
        }
    }

    // A: lane's share of the tile = x[node = wid*16+col][quad*8 .. ] per kblock
    const float* xrow = x + ((long)wid * 16 + col) * FIN + quad * 8;
    float4 xb[8];
#pragma unroll
    for (int kb = 0; kb < 4; kb++) {
        xb[2 * kb]     = *(const float4*)(xrow + kb * 32);
        xb[2 * kb + 1] = *(const float4*)(xrow + kb * 32 + 4);
    }
    f32x4 acc0 = {0.f, 0.f, 0.f, 0.f}, acc1 = {0.f, 0.f, 0.f, 0.f};
#pragma unroll
    for (int kb = 0; kb < 4; kb++) {
        float4 a0 = xb[2 * kb], a1 = xb[2 * kb + 1];
        bf16x8 af;
        af[0] = (short)f2bf(a0.x); af[1] = (short)f2bf(a0.y);
        af[2] = (short)f2bf(a0.z); af[3] = (short)f2bf(a0.w);
        af[4] = (short)f2bf(a1.x); af[5] = (short)f2bf(a1.y);
        af[6] = (short)f2bf(a1.z); af[7] = (short)f2bf(a1.w);
        acc0 = __builtin_amdgcn_mfma_f32_16x16x32_bf16(af, bfrag[0][kb], acc0, 0, 0, 0);
        acc1 = __builtin_amdgcn_mfma_f32_16x16x32_bf16(af, bfrag[1][kb], acc1, 0, 0, 0);
    }

    // C layout: col = lane&15, row = quad*4 + r
    float b1v = b1[col];
#pragma unroll
    for (int r = 0; r < 4; r++) {
        long node = (long)wid * 16 + quad * 4 + r;
        float a0 = acc0[r], a1 = acc1[r];
        xa[node * HID + col] = a0 - a1 + b1v;
        float dn = dinv[node];
        xb8[node * HID + col] = (unsigned char)f2e4m3(dn * a1);
    }
}

// R12-verbatim proj2 epilogue for one node (acc already p-reduced).
static __device__ __forceinline__ void proj2_epi(
    long n, int lane, float dn, const float4 xav, const float* acc,
    const float* __restrict__ W0, const float* __restrict__ W1,
    const float* __restrict__ b2, float* __restrict__ ha,
    unsigned char* __restrict__ hb8) {
    float hq0 = fmaxf(xav.x + dn * acc[0], 0.f);
    float hq1 = fmaxf(xav.y + dn * acc[1], 0.f);
    float hq2 = fmaxf(xav.z + dn * acc[2], 0.f);
    float hq3 = fmaxf(xav.w + dn * acc[3], 0.f);
    // broadcast h[16] wave-wide: source lane a (a=0..3) has d==a, p==0
    float h[16];
#pragma unroll
    for (int a = 0; a < 4; a++) {
        h[4 * a + 0] = __shfl(hq0, a, 64);
        h[4 * a + 1] = __shfl(hq1, a, 64);
        h[4 * a + 2] = __shfl(hq2, a, 64);
        h[4 * a + 3] = __shfl(hq3, a, 64);
    }
    int m = lane >> 5, o = lane & 31;
    const float* Wm = m ? W1 : W0;
    float acc2 = 0.f;
#pragma unroll
    for (int k = 0; k < HID; k++) acc2 += h[k] * Wm[k * NCLS + o];
    float other = __shfl_xor(acc2, 32);   // m==0 lanes receive accB
    if (m == 0) {
        ha[n * NCLS + o] = acc2 - other + b2[o];
    } else {
        unsigned int c0 = f2e4m3(dn * acc2);
        unsigned int c1 = __shfl_down(c0, 1);
        unsigned int c2 = __shfl_down(c0, 2);
        unsigned int c3 = __shfl_down(c0, 3);
        if ((o & 3) == 0)
            *(unsigned int*)(hb8 + n * NCLS + o) =
                c0 | (c1 << 8) | (c2 << 16) | (c3 << 24);
    }
}

// Fused layer-1 gather + layer-2 projection (R15 dual-node).
//  1 wave = adjacent node pair (2w, 2w+1); the two gather chains interleaved
//  for 2x latency hiding; epilogues sequential (R12-verbatim math).
//  lane = (d = dword 0..3, p = edge parity 0..15).
__global__ __launch_bounds__(256) void k_gather1_proj2(
    const int* __restrict__ rowptr, const unsigned int* __restrict__ partC,
    const float* __restrict__ dinv, const unsigned char* __restrict__ xb8,
    const float* __restrict__ xa, const float* __restrict__ W0,
    const float* __restrict__ W1, const float* __restrict__ b2,
    float* __restrict__ ha, unsigned char* __restrict__ hb8) {
    long t = (long)blockIdx.x * 256 + threadIdx.x;
    int w = (int)(t >> 6);
    if (w >= NPAIR) return;
    int lane = threadIdx.x & 63;
    int d = lane & 3, p = lane >> 2;
    long n0 = (long)w * 2, n1 = n0 + 1;

    int s0 = rowptr[n0], e0 = rowptr[n0 + 1], e1 = rowptr[n0 + 2];
    float2 dnv = *(const float2*)(dinv + n0);
    float4 xav0 = *(const float4*)(xa + n0 * HID + d * 4);
    float4 xav1 = *(const float4*)(xa + n1 * HID + d * 4);

    float acc0[4] = {0.f, 0.f, 0.f, 0.f};
    float acc1[4] = {0.f, 0.f, 0.f, 0.f};
    int j0 = s0 + p, j1 = e0 + p;      // n1's range starts at e0
    while ((j0 < e0) | (j1 < e1)) {
        if (j0 < e0) {
            unsigned int u = partC[j0];
            unsigned int v = *(const unsigned int*)(xb8 + (u & 0x1FFFF) * HID + d * 4);
            fp8x4_fma(v, wdec(u), acc0);
            j0 += 16;
        }
        if (j1 < e1) {
            unsigned int u = partC[j1];
            unsigned int v = *(const unsigned int*)(xb8 + (u & 0x1FFFF) * HID + d * 4);
            fp8x4_fma(v, wdec(u), acc1);
            j1 += 16;
        }
    }
    // interleaved p-reduce: two independent DS chains
#pragma unroll
    for (int i = 0; i < 4; i++) {
        acc0[i] += __shfl_xor(acc0[i], 4);  acc1[i] += __shfl_xor(acc1[i], 4);
        acc0[i] += __shfl_xor(acc0[i], 8);  acc1[i] += __shfl_xor(acc1[i], 8);
        acc0[i] += __shfl_xor(acc0[i], 16); acc1[i] += __shfl_xor(acc1[i], 16);
        acc0[i] += __shfl_xor(acc0[i], 32); acc1[i] += __shfl_xor(acc1[i], 32);
    }
    proj2_epi(n0, lane, dnv.x, xav0, acc0, W0, W1, b2, ha, hb8);
    proj2_epi(n1, lane, dnv.y, xav1, acc1, W0, W1, b2, ha, hb8);
}

// R12-verbatim log-softmax epilogue for one node (acc already p-reduced).
static __device__ __forceinline__ void lsm_epi(
    long n, int lane, float dn, const float4 hv, const float* acc,
    float* __restrict__ out) {
    int d = lane & 7, p = lane >> 3;
    float v0 = dn * acc[0] + hv.x;
    float v1 = dn * acc[1] + hv.y;
    float v2 = dn * acc[2] + hv.z;
    float v3 = dn * acc[3] + hv.w;
    float m = fmaxf(fmaxf(v0, v1), fmaxf(v2, v3));
    m = fmaxf(m, __shfl_xor(m, 1));
    m = fmaxf(m, __shfl_xor(m, 2));
    m = fmaxf(m, __shfl_xor(m, 4));
    float sum = __expf(v0 - m) + __expf(v1 - m) + __expf(v2 - m) + __expf(v3 - m);
    sum += __shfl_xor(sum, 1);
    sum += __shfl_xor(sum, 2);
    sum += __shfl_xor(sum, 4);
    float ls = logf(sum);
    if (p == 0) {
        float4 o; o.x = v0 - m - ls; o.y = v1 - m - ls;
        o.z = v2 - m - ls; o.w = v3 - m - ls;
        *(float4*)(out + n * NCLS + d * 4) = o;
    }
}

// out[n,:] = log_softmax(ha[n,:] + dinv[n]*sum_j w_j*hb'[c_j,:]).
// R15 dual-node: 1 wave = pair (2w, 2w+1), gather chains interleaved.
// lane = (d = dword 0..7, p = edge parity 0..7); per-node stride 8 (same
// summation order as R12's unroll-2).
__global__ __launch_bounds__(256) void k_gather2_lsm(
    const int* __restrict__ rowptr, const unsigned int* __restrict__ partC,
    const float* __restrict__ dinv, const float* __restrict__ ha,
    const unsigned char* __restrict__ hb8, float* __restrict__ out) {
    long t = (long)blockIdx.x * 256 + threadIdx.x;
    int w = (int)(t >> 6);
    if (w >= NPAIR) return;
    int lane = threadIdx.x & 63;
    int d = lane & 7, p = lane >> 3;
    long n0 = (long)w * 2, n1 = n0 + 1;

    int s0 = rowptr[n0], e0 = rowptr[n0 + 1], e1 = rowptr[n0 + 2];
    float2 dnv = *(const float2*)(dinv + n0);
    float4 hv0 = *(const float4*)(ha + n0 * NCLS + d * 4);
    float4 hv1 = *(const float4*)(ha + n1 * NCLS + d * 4);

    float acc0[4] = {0.f, 0.f, 0.f, 0.f};
    float acc1[4] = {0.f, 0.f, 0.f, 0.f};
    int j0 = s0 + p, j1 = e0 + p;
    while ((j0 < e0) | (j1 < e1)) {
        if (j0 < e0) {
            unsigned int u = partC[j0];
            unsigned int v = *(const unsigned int*)(hb8 + (u & 0x1FFFF) * NCLS + d * 4);
            fp8x4_fma(v, wdec(u), acc0);
            j0 += 8;
        }
        if (j1 < e1) {
            unsigned int u = partC[j1];
            unsigned int v = *(const unsigned int*)(hb8 + (u & 0x1FFFF) * NCLS + d * 4);
            fp8x4_fma(v, wdec(u), acc1);
            j1 += 8;
        }
    }
#pragma unroll
    for (int i = 0; i < 4; i++) {
        acc0[i] += __shfl_xor(acc0[i], 8);  acc1[i] += __shfl_xor(acc1[i], 8);
        acc0[i] += __shfl_xor(acc0[i], 16); acc1[i] += __shfl_xor(acc1[i], 16);
        acc0[i] += __shfl_xor(acc0[i], 32); acc1[i] += __shfl_xor(acc1[i], 32);
    }
    lsm_epi(n0, lane, dnv.x, hv0, acc0, out);
    lsm_epi(n1, lane, dnv.y, hv1, acc1, out);
}

extern "C" void kernel_launch(void* const* d_in, const int* in_sizes, int n_in,
                              void* d_out, int out_size, void* d_ws, size_t ws_size,
                              hipStream_t stream) {
    const float* x    = (const float*)d_in[0];
    const int*   ei   = (const int*)d_in[1];
    const float* ew   = (const float*)d_in[2];
    const float* W1_0 = (const float*)d_in[3];
    const float* W1_1 = (const float*)d_in[4];
    const float* b1   = (const float*)d_in[5];
    const float* W2_0 = (const float*)d_in[6];
    const float* W2_1 = (const float*)d_in[7];
    const float* b2   = (const float*)d_in[8];
    float* out = (float*)d_out;

    const int* row = ei;
    const int* col = ei + NE;

    char* ws = (char*)d_ws;
    int2*  partS     = (int2*)ws;                 ws += sizeof(int2) * (long)NBKT * CAP;
    unsigned int* partC = (unsigned int*)ws;      ws += sizeof(int) * NE;
    int*   bucketCursor = (int*)ws;               ws += sizeof(int) * NBKT;
    int*   rowptr    = (int*)ws;                  ws += sizeof(int) * (NN + 4);
    float* dinv      = (float*)ws;                ws += sizeof(float) * NN;
    float* xa        = (float*)ws;                ws += sizeof(float) * NN * HID;
    float* ha        = (float*)ws;                ws += sizeof(float) * NN * NCLS;
    unsigned char* xb8 = (unsigned char*)ws;      ws += sizeof(char) * NN * HID;
    unsigned char* hb8 = (unsigned char*)ws;      ws += sizeof(char) * NN * NCLS;

    k_zero_cur<<<(NBKT + 255) / 256, 256, 0, stream>>>(bucketCursor);
    k_partition<<<GP, 256, 0, stream>>>(row, col, ew, bucketCursor, partS);
    k_bucket_sort<<<NBKT, 256, 0, stream>>>(partS, bucketCursor, partC, rowptr, dinv);
    k_proj1<<<(NTILE * 64 + 255) / 256, 256, 0, stream>>>(x, W1_0, W1_1, b1, dinv, xa, xb8);
    {
        long th = (long)NPAIR * 64;
        k_gather1_proj2<<<(int)((th + 255) / 256), 256, 0, stream>>>(
            rowptr, partC, dinv, xb8, xa, W2_0, W2_1, b2, ha, hb8);
    }
    {
        long th = (long)NPAIR * 64;
        k_gather2_lsm<<<(int)((th + 255) / 256), 256, 0, stream>>>(rowptr, partC, dinv, ha, hb8, out);
    }
}

// Round 5
// 213.819 us; speedup vs baseline: 1.1587x; 1.0970x over previous
//
#include <hip/hip_runtime.h>
#include <hip/hip_bf16.h>

// DFAChebNet forward.
//  layer: x@W0 + (agg(x)-x)@W1 + b == x@(W0-W1) + agg(x@W1) + b   (project first)
//  aggregation: CSR pull-gather; CSR built by LDS-staged counting sort.
//  R16: algebraic restructure of layer 2 via linearity:
//    sum_j w_j dinv_j (h_j@W2_1) == (sum_j w_j dinv_j h_j)@W2_1
//  so BOTH gather kernels are now lean 16-wide fp8 gathers with tiny
//  epilogues (no per-node matvec, no 16-shuffle broadcasts, no W2 loads):
//    k_gather1: h = relu(xa + dn*agg(xb8)); store h16 (bf16), h8 = fp8(dn*h)
//    k_gather2: g16 = bf16(dn * agg(h8))
//    k_lsm (new, MFMA): [h16;g16] @ [W2_0-W2_1 ; W2_1] (two 16x16x32 bf16
//    MFMAs per 16-node tile, K=32 concat) + b2 + log-softmax. Replaces the
//    per-node epilogue mass that dominated k_gather1_proj2 (R14/R15 showed
//    in-wave epilogues are the cost). ha (25.6MB RW) + hb8 eliminated.
//  Gather loops keep R15 dual-node interleave (measured best gather form).

#include <hip/hip_fp16.h>

constexpr int NN   = 100000;
constexpr int NE   = 1600000;
constexpr int FIN  = 128;
constexpr int HID  = 16;
constexpr int NCLS = 32;

constexpr int RB    = 256;                         // rows per bucket
constexpr int NBKT  = (NN + RB - 1) / RB;          // 391
constexpr int EPB   = 4096;                        // edges per partition block
constexpr int EPT   = EPB / 256;                   // 16 edges per thread
constexpr int GP    = (NE + EPB - 1) / EPB;        // 391
constexpr int CAP   = 8192;                        // bucket slot capacity (mean 4096)
constexpr int NTILE = NN / 16;                     // 6250 MFMA tiles (exact)
constexpr int NPAIR = NN / 2;                      // 50000 dual-node waves

typedef float f32x2 __attribute__((ext_vector_type(2)));
typedef float f32x4 __attribute__((ext_vector_type(4)));
typedef short bf16x8 __attribute__((ext_vector_type(8)));

#if defined(__has_builtin)
#if __has_builtin(__builtin_amdgcn_cvt_pk_f32_fp8)
#define HAVE_CVT_FP8 1
#endif
#endif

// fp8 e4m3fn encode (RNE, subnormals flushed to 0, clamp at 448)
static __device__ __forceinline__ unsigned int f2e4m3(float f) {
    union { float f; unsigned int u; } v; v.f = f;
    unsigned int s = (v.u >> 24) & 0x80u;
    unsigned int au = v.u & 0x7fffffffu;
    if (au > 0x43E00000u) au = 0x43E00000u;        // clamp to 448
    au += 0x7ffffu + ((au >> 20) & 1u);            // RNE into 3-bit mantissa
    int e4 = (int)(au >> 23) - 120;                // 127-7
    unsigned int m = (au >> 20) & 7u;
    unsigned int byte = (e4 <= 0) ? 0u : (((unsigned int)e4 << 3) | m);
    return s | byte;
}
// 4 packed fp8 -> acc[0..3] += w * val
static __device__ __forceinline__ void fp8x4_fma(unsigned int v, float w, float* acc) {
#ifdef HAVE_CVT_FP8
    f32x2 lo = __builtin_amdgcn_cvt_pk_f32_fp8((int)v, false);
    f32x2 hi = __builtin_amdgcn_cvt_pk_f32_fp8((int)v, true);
    acc[0] += w * lo.x; acc[1] += w * lo.y;
    acc[2] += w * hi.x; acc[3] += w * hi.y;
#else
#pragma unroll
    for (int i = 0; i < 4; i++) {
        unsigned int b = (v >> (8 * i)) & 0xffu;
        float f = __int_as_float((int)(((b & 0x80u) << 24) | ((b & 0x7fu) << 20))) * 0x1p120f;
        acc[i] += w * f;
    }
#endif
}
// bf16 RNE
static __device__ __forceinline__ unsigned short f2bf(float f) {
    union { float f; unsigned int u; } v; v.f = f;
    unsigned int r = v.u + 0x7fffu + ((v.u >> 16) & 1u);
    return (unsigned short)(r >> 16);
}
static __device__ __forceinline__ float bf2f(unsigned short b) {
    union { unsigned int u; float f; } v; v.u = ((unsigned int)b) << 16;
    return v.f;
}
// edge record: col(17 bits) | w(15 bits = signless bf16, RNE)
static __device__ __forceinline__ unsigned int wpack(float wf) {
    unsigned int b = __float_as_uint(wf) + 0x8000u;
    return (b >> 16) & 0x7fffu;
}
static __device__ __forceinline__ float wdec(unsigned int u) {
    return __uint_as_float((u >> 17) << 16);
}

// ---- zero the bucket cursors ----
__global__ void k_zero_cur(int* __restrict__ bucketCursor) {
    int i = blockIdx.x * blockDim.x + threadIdx.x;
    if (i < NBKT) bucketCursor[i] = 0;
}

// ---- pass B: LDS-staged partition; atomic reservation into slotted buffer ----
__global__ __launch_bounds__(256) void k_partition(
    const int* __restrict__ row, const int* __restrict__ col,
    const float* __restrict__ w, int* __restrict__ bucketCursor,
    int2* __restrict__ partS) {
    __shared__ int2 stage[EPB];              // 32KB
    __shared__ unsigned short sbkt[EPB];     // 8KB
    __shared__ int cnt[NBKT];
    __shared__ int lofs[NBKT];
    __shared__ int cursor[NBKT];
    __shared__ int gbase[NBKT];
    __shared__ int sa[512], sb[512];
    int tid = threadIdx.x;
    long ebase = (long)blockIdx.x * EPB;
    int rr[EPT]; int cc[EPT]; float wv[EPT];
#pragma unroll
    for (int i = 0; i < EPT; i++) {
        long e = ebase + i * 256 + tid;
        if (e < NE) { rr[i] = row[e]; cc[i] = col[e]; wv[i] = w[e]; }
        else rr[i] = -1;
    }
    for (int i = tid; i < NBKT; i += 256) cnt[i] = 0;
    __syncthreads();
#pragma unroll
    for (int i = 0; i < EPT; i++)
        if (rr[i] >= 0) atomicAdd(&cnt[rr[i] >> 8], 1);
    __syncthreads();
    for (int i = tid; i < 512; i += 256) sa[i] = (i < NBKT) ? cnt[i] : 0;
    __syncthreads();
    int* src = sa; int* dst = sb;
    for (int off = 1; off < 512; off <<= 1) {
        for (int i = tid; i < 512; i += 256)
            dst[i] = src[i] + ((i >= off) ? src[i - off] : 0);
        __syncthreads();
        int* t = src; src = dst; dst = t;
    }
    for (int i = tid; i < NBKT; i += 256) {
        int ex = src[i] - cnt[i];
        lofs[i] = ex;
        cursor[i] = ex;
        int go = (cnt[i] > 0) ? atomicAdd(&bucketCursor[i], cnt[i]) : 0;
        gbase[i] = i * CAP + go;
    }
    __syncthreads();
#pragma unroll
    for (int i = 0; i < EPT; i++) {
        if (rr[i] >= 0) {
            int b = rr[i] >> 8;
            int p = atomicAdd(&cursor[b], 1);
            int2 v;
            v.x = cc[i] | ((rr[i] & 255) << 17);
            v.y = __float_as_int(wv[i]);
            stage[p] = v;
            sbkt[p] = (unsigned short)b;
        }
    }
    __syncthreads();
    int total = (int)min((long)EPB, NE - ebase);
    for (int i = tid; i < total; i += 256) {
        int b = sbkt[i];
        partS[gbase[b] + (i - lofs[b])] = stage[i];
    }
}

// ---- pass C: per-bucket sort by row; direct scatter to packed 4B CSR.
// No 64KB LDS stage: partC bucket region is block-private, L2 absorbs the 4B
// scattered writes. dinv via LDS float atomics. Bucket prefix-scan inlined.
__global__ __launch_bounds__(256) void k_bucket_sort(
    const int2* __restrict__ partS, const int* __restrict__ bucketCursor,
    unsigned int* __restrict__ partC, int* __restrict__ rowptr,
    float* __restrict__ dinv) {
    __shared__ int hist[RB];
    __shared__ int cursor[RB];
    __shared__ float dsum[RB];
    __shared__ int wtot[4];
    __shared__ int red[4];
    int b = blockIdx.x;
    int tid = threadIdx.x;
    int lane = tid & 63, wv = tid >> 6;
    // inline exclusive scan: start = sum_{i<b} count_i
    int partial = 0;
    for (int i = tid; i < b; i += 256) partial += bucketCursor[i];
#pragma unroll
    for (int off = 1; off < 64; off <<= 1) partial += __shfl_xor(partial, off, 64);
    if (lane == 0) red[wv] = partial;
    hist[tid] = 0;
    dsum[tid] = 0.f;
    __syncthreads();
    int start = red[0] + red[1] + red[2] + red[3];
    int count = bucketCursor[b];
    const int2* src = partS + (long)b * CAP;
    for (int i = tid; i < count; i += 256)
        atomicAdd(&hist[((unsigned)src[i].x >> 17) & 255], 1);
    __syncthreads();
    int v = hist[tid];
    int sc = v;
#pragma unroll
    for (int off = 1; off < 64; off <<= 1) {
        int up = __shfl_up(sc, off, 64);
        if (lane >= off) sc += up;
    }
    if (lane == 63) wtot[wv] = sc;
    __syncthreads();
    int add = 0;
    for (int w2 = 0; w2 < wv; w2++) add += wtot[w2];
    int ex = sc + add - v;
    int node = b * RB + tid;
    if (node <= NN) rowptr[node] = start + ex;   // node==NN -> NE (last bucket)
    cursor[tid] = ex;
    __syncthreads();
    for (int i = tid; i < count; i += 256) {
        int2 p = src[i];
        int rl = ((unsigned)p.x >> 17) & 255;
        int pos = atomicAdd(&cursor[rl], 1);
        float wf = __int_as_float(p.y);
        partC[start + pos] = ((unsigned)p.x & 0x1FFFFu) | (wpack(wf) << 17);
        atomicAdd(&dsum[rl], wf);
    }
    __syncthreads();
    if (node < NN) {
        float dsv = dsum[tid];
        dinv[node] = dsv > 0.f ? rsqrtf(dsv) : 0.f;
    }
}

// xa = x@(W1_0-W1_1)+b1 (fp32) ; xb' = dinv[n] * (x@W1_1) (fp8 e4m3).
// MFMA 16x16x32 bf16: 1 wave = 16 nodes. W frags in VGPRs (built once);
// A = 8 float4 loads/lane; acc0 = x@W1_0, acc1 = x@W1_1.
__global__ __launch_bounds__(256) void k_proj1(
    const float* __restrict__ x, const float* __restrict__ W0,
    const float* __restrict__ W1, const float* __restrict__ b1,
    const float* __restrict__ dinv,
    float* __restrict__ xa, unsigned char* __restrict__ xb8) {
    int wid = (int)(((long)blockIdx.x * 256 + threadIdx.x) >> 6);   // tile id
    if (wid >= NTILE) return;
    int lane = threadIdx.x & 63;
    int col = lane & 15, quad = lane >> 4;

    // B fragments: B[k = kb*32 + quad*8 + j][n = col], once per wave.
    bf16x8 bfrag[2][4];
#pragma unroll
    for (int mat = 0; mat < 2; mat++) {
        const float* W = mat ? W1 : W0;
#pragma unroll
        for (int kb = 0; kb < 4; kb++) {
            bf16x8 f;
#pragma unroll
            for (int j = 0; j < 8; j++)
                f[j] = (short)f2bf(W[(kb * 32 + quad * 8 + j) * HID + col]);
            bfrag[mat][kb] = f;
        }
    }

    // A: lane's share of the tile = x[node = wid*16+col][quad*8 .. ] per kblock
    const float* xrow = x + ((long)wid * 16 + col) * FIN + quad * 8;
    float4 xb[8];
#pragma unroll
    for (int kb = 0; kb < 4; kb++) {
        xb[2 * kb]     = *(const float4*)(xrow + kb * 32);
        xb[2 * kb + 1] = *(const float4*)(xrow + kb * 32 + 4);
    }
    f32x4 acc0 = {0.f, 0.f, 0.f, 0.f}, acc1 = {0.f, 0.f, 0.f, 0.f};
#pragma unroll
    for (int kb = 0; kb < 4; kb++) {
        float4 a0 = xb[2 * kb], a1 = xb[2 * kb + 1];
        bf16x8 af;
        af[0] = (short)f2bf(a0.x); af[1] = (short)f2bf(a0.y);
        af[2] = (short)f2bf(a0.z); af[3] = (short)f2bf(a0.w);
        af[4] = (short)f2bf(a1.x); af[5] = (short)f2bf(a1.y);
        af[6] = (short)f2bf(a1.z); af[7] = (short)f2bf(a1.w);
        acc0 = __builtin_amdgcn_mfma_f32_16x16x32_bf16(af, bfrag[0][kb], acc0, 0, 0, 0);
        acc1 = __builtin_amdgcn_mfma_f32_16x16x32_bf16(af, bfrag[1][kb], acc1, 0, 0, 0);
    }

    // C layout: col = lane&15, row = quad*4 + r
    float b1v = b1[col];
#pragma unroll
    for (int r = 0; r < 4; r++) {
        long node = (long)wid * 16 + quad * 4 + r;
        float a0 = acc0[r], a1 = acc1[r];
        xa[node * HID + col] = a0 - a1 + b1v;
        float dn = dinv[node];
        xb8[node * HID + col] = (unsigned char)f2e4m3(dn * a1);
    }
}

// Layer-1 gather, lean (R16). 1 wave = adjacent node pair, chains interleaved.
//  h = relu(xa + dn*agg(xb8)); store h16 = bf16(h), h8 = fp8(dn*h).
//  lane = (d = dword 0..3, p = edge parity 0..15). Epilogue: 4 lanes store
//  8B+4B each -- no matvec, no broadcasts (moved to k_lsm).
__global__ __launch_bounds__(256) void k_gather1(
    const int* __restrict__ rowptr, const unsigned int* __restrict__ partC,
    const float* __restrict__ dinv, const unsigned char* __restrict__ xb8,
    const float* __restrict__ xa,
    unsigned short* __restrict__ h16, unsigned char* __restrict__ h8) {
    long t = (long)blockIdx.x * 256 + threadIdx.x;
    int w = (int)(t >> 6);
    if (w >= NPAIR) return;
    int lane = threadIdx.x & 63;
    int d = lane & 3, p = lane >> 2;
    long n0 = (long)w * 2, n1 = n0 + 1;

    int s0 = rowptr[n0], e0 = rowptr[n0 + 1], e1 = rowptr[n0 + 2];
    float2 dnv = *(const float2*)(dinv + n0);
    float4 xav0 = *(const float4*)(xa + n0 * HID + d * 4);
    float4 xav1 = *(const float4*)(xa + n1 * HID + d * 4);

    float acc0[4] = {0.f, 0.f, 0.f, 0.f};
    float acc1[4] = {0.f, 0.f, 0.f, 0.f};
    int j0 = s0 + p, j1 = e0 + p;      // n1's range starts at e0
    while ((j0 < e0) | (j1 < e1)) {
        if (j0 < e0) {
            unsigned int u = partC[j0];
            unsigned int v = *(const unsigned int*)(xb8 + (u & 0x1FFFF) * HID + d * 4);
            fp8x4_fma(v, wdec(u), acc0);
            j0 += 16;
        }
        if (j1 < e1) {
            unsigned int u = partC[j1];
            unsigned int v = *(const unsigned int*)(xb8 + (u & 0x1FFFF) * HID + d * 4);
            fp8x4_fma(v, wdec(u), acc1);
            j1 += 16;
        }
    }
#pragma unroll
    for (int i = 0; i < 4; i++) {
        acc0[i] += __shfl_xor(acc0[i], 4);  acc1[i] += __shfl_xor(acc1[i], 4);
        acc0[i] += __shfl_xor(acc0[i], 8);  acc1[i] += __shfl_xor(acc1[i], 8);
        acc0[i] += __shfl_xor(acc0[i], 16); acc1[i] += __shfl_xor(acc1[i], 16);
        acc0[i] += __shfl_xor(acc0[i], 32); acc1[i] += __shfl_xor(acc1[i], 32);
    }
    if (p == 0) {   // lanes 0..3 (lane == d)
        float h0[4], h1[4];
        h0[0] = fmaxf(xav0.x + dnv.x * acc0[0], 0.f);
        h0[1] = fmaxf(xav0.y + dnv.x * acc0[1], 0.f);
        h0[2] = fmaxf(xav0.z + dnv.x * acc0[2], 0.f);
        h0[3] = fmaxf(xav0.w + dnv.x * acc0[3], 0.f);
        h1[0] = fmaxf(xav1.x + dnv.y * acc1[0], 0.f);
        h1[1] = fmaxf(xav1.y + dnv.y * acc1[1], 0.f);
        h1[2] = fmaxf(xav1.z + dnv.y * acc1[2], 0.f);
        h1[3] = fmaxf(xav1.w + dnv.y * acc1[3], 0.f);
        ushort4 u0, u1;
        u0.x = f2bf(h0[0]); u0.y = f2bf(h0[1]); u0.z = f2bf(h0[2]); u0.w = f2bf(h0[3]);
        u1.x = f2bf(h1[0]); u1.y = f2bf(h1[1]); u1.z = f2bf(h1[2]); u1.w = f2bf(h1[3]);
        *(ushort4*)(h16 + n0 * HID + d * 4) = u0;
        *(ushort4*)(h16 + n1 * HID + d * 4) = u1;
        unsigned int p0 = f2e4m3(dnv.x * h0[0]) | (f2e4m3(dnv.x * h0[1]) << 8)
                        | (f2e4m3(dnv.x * h0[2]) << 16) | (f2e4m3(dnv.x * h0[3]) << 24);
        unsigned int p1 = f2e4m3(dnv.y * h1[0]) | (f2e4m3(dnv.y * h1[1]) << 8)
                        | (f2e4m3(dnv.y * h1[2]) << 16) | (f2e4m3(dnv.y * h1[3]) << 24);
        *(unsigned int*)(h8 + n0 * HID + d * 4) = p0;
        *(unsigned int*)(h8 + n1 * HID + d * 4) = p1;
    }
}

// Layer-2 gather, lean (R16). g16 = bf16(dn * sum_j w_j * h8[c_j,:]).
// Same structure as k_gather1; epilogue = one 8B store per d-lane per node.
__global__ __launch_bounds__(256) void k_gather2(
    const int* __restrict__ rowptr, const unsigned int* __restrict__ partC,
    const float* __restrict__ dinv, const unsigned char* __restrict__ h8,
    unsigned short* __restrict__ g16) {
    long t = (long)blockIdx.x * 256 + threadIdx.x;
    int w = (int)(t >> 6);
    if (w >= NPAIR) return;
    int lane = threadIdx.x & 63;
    int d = lane & 3, p = lane >> 2;
    long n0 = (long)w * 2, n1 = n0 + 1;

    int s0 = rowptr[n0], e0 = rowptr[n0 + 1], e1 = rowptr[n0 + 2];
    float2 dnv = *(const float2*)(dinv + n0);

    float acc0[4] = {0.f, 0.f, 0.f, 0.f};
    float acc1[4] = {0.f, 0.f, 0.f, 0.f};
    int j0 = s0 + p, j1 = e0 + p;
    while ((j0 < e0) | (j1 < e1)) {
        if (j0 < e0) {
            unsigned int u = partC[j0];
            unsigned int v = *(const unsigned int*)(h8 + (u & 0x1FFFF) * HID + d * 4);
            fp8x4_fma(v, wdec(u), acc0);
            j0 += 16;
        }
        if (j1 < e1) {
            unsigned int u = partC[j1];
            unsigned int v = *(const unsigned int*)(h8 + (u & 0x1FFFF) * HID + d * 4);
            fp8x4_fma(v, wdec(u), acc1);
            j1 += 16;
        }
    }
#pragma unroll
    for (int i = 0; i < 4; i++) {
        acc0[i] += __shfl_xor(acc0[i], 4);  acc1[i] += __shfl_xor(acc1[i], 4);
        acc0[i] += __shfl_xor(acc0[i], 8);  acc1[i] += __shfl_xor(acc1[i], 8);
        acc0[i] += __shfl_xor(acc0[i], 16); acc1[i] += __shfl_xor(acc1[i], 16);
        acc0[i] += __shfl_xor(acc0[i], 32); acc1[i] += __shfl_xor(acc1[i], 32);
    }
    if (p == 0) {
        ushort4 u0, u1;
        u0.x = f2bf(dnv.x * acc0[0]); u0.y = f2bf(dnv.x * acc0[1]);
        u0.z = f2bf(dnv.x * acc0[2]); u0.w = f2bf(dnv.x * acc0[3]);
        u1.x = f2bf(dnv.y * acc1[0]); u1.y = f2bf(dnv.y * acc1[1]);
        u1.z = f2bf(dnv.y * acc1[2]); u1.w = f2bf(dnv.y * acc1[3]);
        *(ushort4*)(g16 + n0 * HID + d * 4) = u0;
        *(ushort4*)(g16 + n1 * HID + d * 4) = u1;
    }
}

// Final projection + log-softmax (R16, MFMA). 1 wave = 16-node tile.
//  v[n,:] = h16[n]@(W2_0-W2_1) + g16[n]@W2_1 + b2  (K=32 concat => two
//  16x16x32 bf16 MFMAs, class blocks 0-15 / 16-31)
//  out[n,:] = v - max - log(sum(exp(v-max)))  (reduce over 16-lane groups)
__global__ __launch_bounds__(256) void k_lsm(
    const unsigned short* __restrict__ h16, const unsigned short* __restrict__ g16,
    const float* __restrict__ W0, const float* __restrict__ W1,
    const float* __restrict__ b2, float* __restrict__ out) {
    int wid = (int)(((long)blockIdx.x * 256 + threadIdx.x) >> 6);
    if (wid >= NTILE) return;
    int lane = threadIdx.x & 63;
    int col = lane & 15, quad = lane >> 4;

    // B frags for class blocks c=0,1: Bcomb[k][o] = k<16 ? W0[k][o]-W1[k][o]
    //                                              : W1[k-16][o]
    bf16x8 bfrag[2];
#pragma unroll
    for (int c = 0; c < 2; c++) {
        bf16x8 f;
        if (quad < 2) {
#pragma unroll
            for (int j = 0; j < 8; j++) {
                int k = quad * 8 + j;
                f[j] = (short)f2bf(W0[k * NCLS + col + 16 * c] - W1[k * NCLS + col + 16 * c]);
            }
        } else {
#pragma unroll
            for (int j = 0; j < 8; j++) {
                int k = (quad - 2) * 8 + j;
                f[j] = (short)f2bf(W1[k * NCLS + col + 16 * c]);
            }
        }
        bfrag[c] = f;
    }

    // A frag: node = wid*16+col; k = quad*8+j -> quad 0,1: h16, quad 2,3: g16
    long node_a = (long)wid * 16 + col;
    const unsigned short* abase =
        (quad & 2) ? (g16 + node_a * HID + (quad & 1) * 8)
                   : (h16 + node_a * HID + (quad & 1) * 8);
    bf16x8 af = *(const bf16x8*)abase;

    f32x4 c0 = {0.f, 0.f, 0.f, 0.f}, c1 = {0.f, 0.f, 0.f, 0.f};
    c0 = __builtin_amdgcn_mfma_f32_16x16x32_bf16(af, bfrag[0], c0, 0, 0, 0);
    c1 = __builtin_amdgcn_mfma_f32_16x16x32_bf16(af, bfrag[1], c1, 0, 0, 0);

    float b2a = b2[col], b2b = b2[col + 16];
    // C layout: class = col, node = wid*16 + quad*4 + r
#pragma unroll
    for (int r = 0; r < 4; r++) {
        long node = (long)wid * 16 + quad * 4 + r;
        float v0 = c0[r] + b2a;
        float v1 = c1[r] + b2b;
        float m = fmaxf(v0, v1);
        m = fmaxf(m, __shfl_xor(m, 1));
        m = fmaxf(m, __shfl_xor(m, 2));
        m = fmaxf(m, __shfl_xor(m, 4));
        m = fmaxf(m, __shfl_xor(m, 8));
        float sum = __expf(v0 - m) + __expf(v1 - m);
        sum += __shfl_xor(sum, 1);
        sum += __shfl_xor(sum, 2);
        sum += __shfl_xor(sum, 4);
        sum += __shfl_xor(sum, 8);
        float ls = logf(sum);
        out[node * NCLS + col] = v0 - m - ls;
        out[node * NCLS + col + 16] = v1 - m - ls;
    }
}

extern "C" void kernel_launch(void* const* d_in, const int* in_sizes, int n_in,
                              void* d_out, int out_size, void* d_ws, size_t ws_size,
                              hipStream_t stream) {
    const float* x    = (const float*)d_in[0];
    const int*   ei   = (const int*)d_in[1];
    const float* ew   = (const float*)d_in[2];
    const float* W1_0 = (const float*)d_in[3];
    const float* W1_1 = (const float*)d_in[4];
    const float* b1   = (const float*)d_in[5];
    const float* W2_0 = (const float*)d_in[6];
    const float* W2_1 = (const float*)d_in[7];
    const float* b2   = (const float*)d_in[8];
    float* out = (float*)d_out;

    const int* row = ei;
    const int* col = ei + NE;

    char* ws = (char*)d_ws;
    int2*  partS     = (int2*)ws;                 ws += sizeof(int2) * (long)NBKT * CAP;
    unsigned int* partC = (unsigned int*)ws;      ws += sizeof(int) * NE;
    int*   bucketCursor = (int*)ws;               ws += sizeof(int) * NBKT;
    int*   rowptr    = (int*)ws;                  ws += sizeof(int) * (NN + 4);
    float* dinv      = (float*)ws;                ws += sizeof(float) * NN;
    float* xa        = (float*)ws;                ws += sizeof(float) * NN * HID;
    unsigned short* h16 = (unsigned short*)ws;    ws += sizeof(short) * NN * HID;
    unsigned short* g16 = (unsigned short*)ws;    ws += sizeof(short) * NN * HID;
    unsigned char* xb8 = (unsigned char*)ws;      ws += sizeof(char) * NN * HID;
    unsigned char* h8  = (unsigned char*)ws;      ws += sizeof(char) * NN * HID;

    k_zero_cur<<<(NBKT + 255) / 256, 256, 0, stream>>>(bucketCursor);
    k_partition<<<GP, 256, 0, stream>>>(row, col, ew, bucketCursor, partS);
    k_bucket_sort<<<NBKT, 256, 0, stream>>>(partS, bucketCursor, partC, rowptr, dinv);
    k_proj1<<<(NTILE * 64 + 255) / 256, 256, 0, stream>>>(x, W1_0, W1_1, b1, dinv, xa, xb8);
    {
        long th = (long)NPAIR * 64;
        k_gather1<<<(int)((th + 255) / 256), 256, 0, stream>>>(
            rowptr, partC, dinv, xb8, xa, h16, h8);
        k_gather2<<<(int)((th + 255) / 256), 256, 0, stream>>>(
            rowptr, partC, dinv, h8, g16);
    }
    k_lsm<<<(NTILE * 64 + 255) / 256, 256, 0, stream>>>(h16, g16, W2_0, W2_1, b2, out);
}